// Round 9
// baseline (971.553 us; speedup 1.0000x reference)
//
#include <hip/hip_runtime.h>
#include <hip/hip_cooperative_groups.h>
#include <math.h>

namespace cg = cooperative_groups;

#define BB 32
#define NN 8192
#define WW 256
#define RR 4
#define CDIM (3*WW + RR + 3)   // 775
#define EPSF 1e-8f

#define K_SEL 128
#define CAP   256

#define NBLK   256              // cooperative grid: 1 block per CU
#define NTHR   1024
#define BPI    4                // batches per iteration
#define NIT    (BB/BPI)         // 8 iterations
#define BLKPB  (NBLK/BPI)       // 64 blocks per batch
#define ROWSPB (NN/BLKPB)       // 128 rows per block per iteration

typedef float floatx4 __attribute__((ext_vector_type(4)));

// ---- workspace layout (float offsets) ----
#define O_S      0                      // B*N : p = exp(beta*cossim)
#define O_PHI    (O_S     + BB*NN)      // B*N
#define O_ALLOC  (O_PHI   + BB*NN)      // B*N
#define O_PSUM   (O_ALLOC + BB*NN)      // B*64 partial softmax sums

__device__ __forceinline__ float sigmoidf_(float x) { return 1.0f / (1.0f + expf(-x)); }

__global__ __launch_bounds__(NTHR, 4)
void fused_kernel(const float* __restrict__ mem,
                  const float* __restrict__ controls,
                  const float* __restrict__ rw,
                  const float* __restrict__ us,
                  const float* __restrict__ pw,
                  float* __restrict__ ws,
                  float* __restrict__ out) {
    cg::grid_group grid = cg::this_grid();

    __shared__ unsigned hist[4096];            // topk (iter 0 only)
    __shared__ unsigned long long cand[CAP];
    __shared__ unsigned uscan0[1024];
    __shared__ unsigned uscan1[1024];
    __shared__ float dred[64];
    __shared__ int selbin;
    __shared__ unsigned ccnt;

    const int g  = blockIdx.x;
    const int t  = threadIdx.x;
    const int l  = t & 63;
    const int li = l & 15;                     // 16 lanes per row
    const int slot = (t >> 6) * 4 + (l >> 4);  // 0..63 row-pair slot
    const int blk_in_b = g & (BLKPB - 1);

    for (int i = 0; i < NIT; ++i) {
        const int b = i * BPI + (g >> 6);
        const int r0 = blk_in_b * ROWSPB + slot * 2;
        const int r1 = r0 + 1;
        const float* c = controls + (size_t)b * CDIM;

        // ================= phase A: dots + exp, mem -> registers =================
        float4 k4[4];
        float ksq = 0.0f;
#pragma unroll
        for (int k = 0; k < 4; k++) {
            k4[k].x = c[li*4 + k*64 + 0];
            k4[k].y = c[li*4 + k*64 + 1];
            k4[k].z = c[li*4 + k*64 + 2];
            k4[k].w = c[li*4 + k*64 + 3];
            ksq += k4[k].x*k4[k].x + k4[k].y*k4[k].y + k4[k].z*k4[k].z + k4[k].w*k4[k].w;
        }
#pragma unroll
        for (int off = 8; off > 0; off >>= 1) ksq += __shfl_xor(ksq, off, 64);
        float kn = sqrtf(ksq);
        float bx = c[3*WW + RR];
        float beta = 1.0f + fmaxf(bx, 0.0f) + log1pf(expf(-fabsf(bx)));

        const floatx4* row0 = (const floatx4*)(mem + ((size_t)b * NN + r0) * WW);
        const floatx4* row1 = (const floatx4*)(mem + ((size_t)b * NN + r1) * WW);
        floatx4 mA[4], mB[4];
        float dot0 = 0.0f, nn0 = 0.0f, dot1 = 0.0f, nn1 = 0.0f;
#pragma unroll
        for (int k = 0; k < 4; k++) {
            mA[k] = row0[li + k*16];
            dot0 += mA[k].x*k4[k].x + mA[k].y*k4[k].y + mA[k].z*k4[k].z + mA[k].w*k4[k].w;
            nn0  += mA[k].x*mA[k].x + mA[k].y*mA[k].y + mA[k].z*mA[k].z + mA[k].w*mA[k].w;
        }
#pragma unroll
        for (int k = 0; k < 4; k++) {
            mB[k] = row1[li + k*16];
            dot1 += mB[k].x*k4[k].x + mB[k].y*k4[k].y + mB[k].z*k4[k].z + mB[k].w*k4[k].w;
            nn1  += mB[k].x*mB[k].x + mB[k].y*mB[k].y + mB[k].z*mB[k].z + mB[k].w*mB[k].w;
        }
#pragma unroll
        for (int off = 8; off > 0; off >>= 1) {
            dot0 += __shfl_xor(dot0, off, 64);
            nn0  += __shfl_xor(nn0,  off, 64);
            dot1 += __shfl_xor(dot1, off, 64);
            nn1  += __shfl_xor(nn1,  off, 64);
        }
        if (li == 0) {
            float pv0 = expf(dot0 / (kn * sqrtf(nn0) + EPSF) * beta);
            float pv1 = expf(dot1 / (kn * sqrtf(nn1) + EPSF) * beta);
            ws[O_S + (size_t)b * NN + r0] = pv0;
            ws[O_S + (size_t)b * NN + r1] = pv1;
            dred[slot] = pv0 + pv1;
        }
        __syncthreads();
        if (t == 0) {
            float s = 0.0f;
#pragma unroll
            for (int j = 0; j < 64; j++) s += dred[j];
            ws[O_PSUM + (size_t)b * 64 + blk_in_b] = s;
        }

        // ========== iter 0 only: topk/phi/alloc for batch g on blocks 0..31 ==========
        if (i == 0 && g < BB) {
            const int tb = g;
            const float* tc = controls + (size_t)tb * CDIM;
            float fg[RR];
#pragma unroll
            for (int r = 0; r < RR; r++) fg[r] = sigmoidf_(tc[3*WW + r]);

            for (int j = t; j < 4096; j += 1024) hist[j] = 0;
            if (t == 0) { selbin = 0x7FFFFFFF; ccnt = 0; }
            __syncthreads();

            unsigned fb[8];
#pragma unroll
            for (int q = 0; q < 8; q++) {
                int n = t + q * 1024;
                size_t gid = (size_t)tb * NN + n;
                float phi = 1.0f;
#pragma unroll
                for (int r = 0; r < RR; r++)
                    phi *= (1.0f - fg[r] * rw[((size_t)(tb*RR + r)) * NN + n]);
                float u0 = us[gid];
                float u = (u0 + pw[gid] * (1.0f - u0)) * phi;
                float usc = u * (1.0f - EPSF) + EPSF;
                ws[O_PHI   + gid] = phi;
                ws[O_ALLOC + gid] = 0.0f;
                fb[q] = __float_as_uint(usc);
                atomicAdd(&hist[fb[q] >> 19], 1u);
            }
            __syncthreads();

            unsigned h0 = hist[4*t], h1 = hist[4*t+1], h2 = hist[4*t+2], h3 = hist[4*t+3];
            unsigned tot = h0 + h1 + h2 + h3;
            unsigned *a0 = uscan0, *a1 = uscan1;
            a0[t] = tot;
            __syncthreads();
            for (int off = 1; off < 1024; off <<= 1) {
                unsigned v = a0[t];
                if (t >= off) v += a0[t - off];
                a1[t] = v;
                __syncthreads();
                unsigned* tmp = a0; a0 = a1; a1 = tmp;
            }
            unsigned excl = (t == 0) ? 0u : a0[t - 1];
            {
                unsigned cc = excl;
                unsigned hh[4] = {h0, h1, h2, h3};
#pragma unroll
                for (int j = 0; j < 4; j++) {
                    cc += hh[j];
                    if (cc >= K_SEL) { atomicMin(&selbin, 4*t + j); break; }
                }
            }
            __syncthreads();
            int Bsel = selbin;

#pragma unroll
            for (int q = 0; q < 8; q++) {
                if ((int)(fb[q] >> 19) <= Bsel) {
                    unsigned pos = atomicAdd(&ccnt, 1u);
                    if (pos < CAP)
                        cand[pos] = (((unsigned long long)fb[q]) << 32) | (unsigned)(t + q*1024);
                }
            }
            __syncthreads();
            unsigned cnt = min(ccnt, (unsigned)CAP);
            if (t >= cnt && t < CAP) cand[t] = 0x3F800000FFFFFFFFull;
            __syncthreads();

            for (int k = 2; k <= CAP; k <<= 1) {
                for (int j = k >> 1; j > 0; j >>= 1) {
                    if (t < CAP) {
                        int p = t ^ j;
                        if (p > t) {
                            unsigned long long x = cand[t], y = cand[p];
                            bool asc = ((t & k) == 0);
                            if ((x > y) == asc) { cand[t] = y; cand[p] = x; }
                        }
                    }
                    __syncthreads();
                }
            }

            float v = 1.0f;
            if (t < CAP) v = __uint_as_float((unsigned)(cand[t] >> 32));
            float *f0 = (float*)uscan0, *f1 = (float*)uscan1;
            if (t < CAP) f0[t] = v;
            __syncthreads();
            for (int off = 1; off < CAP; off <<= 1) {
                float x = 0.0f;
                if (t < CAP) { x = f0[t]; if (t >= off) x *= f0[t - off]; }
                __syncthreads();
                if (t < CAP) f1[t] = x;
                __syncthreads();
                float* tmp = f0; f0 = f1; f1 = tmp;
            }
            if (t < CAP) {
                float pre = (t == 0) ? 1.0f : f0[t - 1];
                unsigned idx = (unsigned)(cand[t] & 0xFFFFFFFFull);
                if (idx < NN)
                    ws[O_ALLOC + (size_t)tb * NN + idx] = (1.0f - v) * pre;
            }
        }

        __threadfence();
        grid.sync();

        // ================= phase B: finish softmax, update from registers =================
        float v = ws[O_PSUM + (size_t)b * 64 + l];
#pragma unroll
        for (int off = 32; off > 0; off >>= 1) v += __shfl_xor(v, off, 64);
        float iden = 1.0f / v;
        float ag = sigmoidf_(c[3*WW + RR + 1]);
        float wg = sigmoidf_(c[3*WW + RR + 2]);

        float4 e4[4], a4[4];
#pragma unroll
        for (int k = 0; k < 4; k++) {
            int col = li*4 + k*64;
            e4[k].x = sigmoidf_(c[WW + col + 0]);
            e4[k].y = sigmoidf_(c[WW + col + 1]);
            e4[k].z = sigmoidf_(c[WW + col + 2]);
            e4[k].w = sigmoidf_(c[WW + col + 3]);
            a4[k].x = c[2*WW + col + 0];
            a4[k].y = c[2*WW + col + 1];
            a4[k].z = c[2*WW + col + 2];
            a4[k].w = c[2*WW + col + 3];
        }

        float pv0 = ws[O_S     + (size_t)b * NN + r0];
        float al0 = ws[O_ALLOC + (size_t)b * NN + r0];
        float ph0 = ws[O_PHI   + (size_t)b * NN + r0];
        float ww0 = wg * (ag * al0 + (1.0f - ag) * pv0 * iden);
        float pv1 = ws[O_S     + (size_t)b * NN + r1];
        float al1 = ws[O_ALLOC + (size_t)b * NN + r1];
        float ph1 = ws[O_PHI   + (size_t)b * NN + r1];
        float ww1 = wg * (ag * al1 + (1.0f - ag) * pv1 * iden);

        floatx4* o0 = (floatx4*)(out + ((size_t)b * NN + r0) * WW);
        floatx4* o1 = (floatx4*)(out + ((size_t)b * NN + r1) * WW);
#pragma unroll
        for (int k = 0; k < 4; k++) {
            floatx4 o;
            o.x = mA[k].x * (1.0f - ww0 * e4[k].x) * ph0 + ww0 * a4[k].x;
            o.y = mA[k].y * (1.0f - ww0 * e4[k].y) * ph0 + ww0 * a4[k].y;
            o.z = mA[k].z * (1.0f - ww0 * e4[k].z) * ph0 + ww0 * a4[k].z;
            o.w = mA[k].w * (1.0f - ww0 * e4[k].w) * ph0 + ww0 * a4[k].w;
            __builtin_nontemporal_store(o, &o0[li + k*16]);
        }
#pragma unroll
        for (int k = 0; k < 4; k++) {
            floatx4 o;
            o.x = mB[k].x * (1.0f - ww1 * e4[k].x) * ph1 + ww1 * a4[k].x;
            o.y = mB[k].y * (1.0f - ww1 * e4[k].y) * ph1 + ww1 * a4[k].y;
            o.z = mB[k].z * (1.0f - ww1 * e4[k].z) * ph1 + ww1 * a4[k].z;
            o.w = mB[k].w * (1.0f - ww1 * e4[k].w) * ph1 + ww1 * a4[k].w;
            __builtin_nontemporal_store(o, &o1[li + k*16]);
        }
    }
}

extern "C" void kernel_launch(void* const* d_in, const int* in_sizes, int n_in,
                              void* d_out, int out_size, void* d_ws, size_t ws_size,
                              hipStream_t stream) {
    const float* mem      = (const float*)d_in[0];
    const float* controls = (const float*)d_in[1];
    const float* rw       = (const float*)d_in[2];
    const float* us       = (const float*)d_in[3];
    const float* pw       = (const float*)d_in[4];
    float* out = (float*)d_out;
    float* ws  = (float*)d_ws;

    void* args[] = {(void*)&mem, (void*)&controls, (void*)&rw,
                    (void*)&us, (void*)&pw, (void*)&ws, (void*)&out};
    hipLaunchCooperativeKernel((void*)fused_kernel, dim3(NBLK), dim3(NTHR),
                               args, 0, stream);
}

// Round 10
// 818.912 us; speedup vs baseline: 1.1864x; 1.1864x over previous
//
#include <hip/hip_runtime.h>
#include <math.h>

#define BB 32
#define NN 8192
#define WW 256
#define RR 4
#define CDIM (3*WW + RR + 3)   // 775
#define EPSF 1e-8f

#define K_SEL 128
#define CAP   256

#define NBLK2   512             // persistent kernel: 512 blocks x 512 thr (2 blocks/CU guaranteed)
#define NTHR2   512
#define ROWS_PB 32              // rows held in LDS per block per round
#define BLKS_PB 256             // blocks per batch
#define NROUND  16              // 2 batches per round

typedef float floatx4 __attribute__((ext_vector_type(4)));

// ---- workspace layout (float offsets) ----
#define O_PHI    0                      // B*N
#define O_ALLOC  (O_PHI   + BB*NN)      // B*N
#define O_PSUM   (O_ALLOC + BB*NN)      // B*256 partial softmax sums
#define O_CNT    (O_PSUM  + BB*256)     // B ints (arrival counters)

__device__ __forceinline__ float sigmoidf_(float x) { return 1.0f / (1.0f + expf(-x)); }

// ---------- kernel 1: topk/phi/alloc per batch + zero semaphores ----------
__global__ __launch_bounds__(1024) void topk_kernel(const float* __restrict__ controls,
                                                    const float* __restrict__ rw,
                                                    const float* __restrict__ us,
                                                    const float* __restrict__ pw,
                                                    float* __restrict__ ws) {
    __shared__ unsigned hist[4096];
    __shared__ unsigned long long cand[CAP];
    __shared__ unsigned uscan0[1024];
    __shared__ unsigned uscan1[1024];
    __shared__ int selbin;
    __shared__ unsigned ccnt;

    int b = blockIdx.x, t = threadIdx.x;

    // re-zero semaphores/partials every launch (replay-safe)
    if (t < 256) ws[O_PSUM + b*256 + t] = 0.0f;
    if (t == 0) ((int*)(ws + O_CNT))[b] = 0;

    const float* c = controls + (size_t)b * CDIM;
    float fg[RR];
#pragma unroll
    for (int r = 0; r < RR; r++) fg[r] = sigmoidf_(c[3*WW + r]);

    for (int i = t; i < 4096; i += 1024) hist[i] = 0;
    if (t == 0) { selbin = 0x7FFFFFFF; ccnt = 0; }
    __syncthreads();

    unsigned fb[8];
#pragma unroll
    for (int q = 0; q < 8; q++) {
        int n = t + q * 1024;
        size_t gid = (size_t)b * NN + n;
        float phi = 1.0f;
#pragma unroll
        for (int r = 0; r < RR; r++)
            phi *= (1.0f - fg[r] * rw[((size_t)(b*RR + r)) * NN + n]);
        float u0 = us[gid];
        float u = (u0 + pw[gid] * (1.0f - u0)) * phi;
        float usc = u * (1.0f - EPSF) + EPSF;
        ws[O_PHI   + gid] = phi;
        ws[O_ALLOC + gid] = 0.0f;
        fb[q] = __float_as_uint(usc);
        atomicAdd(&hist[fb[q] >> 19], 1u);
    }
    __syncthreads();

    unsigned h0 = hist[4*t], h1 = hist[4*t+1], h2 = hist[4*t+2], h3 = hist[4*t+3];
    unsigned tot = h0 + h1 + h2 + h3;
    unsigned *a0 = uscan0, *a1 = uscan1;
    a0[t] = tot;
    __syncthreads();
    for (int off = 1; off < 1024; off <<= 1) {
        unsigned v = a0[t];
        if (t >= off) v += a0[t - off];
        a1[t] = v;
        __syncthreads();
        unsigned* tmp = a0; a0 = a1; a1 = tmp;
    }
    unsigned excl = (t == 0) ? 0u : a0[t - 1];
    {
        unsigned cc = excl;
        unsigned hh[4] = {h0, h1, h2, h3};
#pragma unroll
        for (int j = 0; j < 4; j++) {
            cc += hh[j];
            if (cc >= K_SEL) { atomicMin(&selbin, 4*t + j); break; }
        }
    }
    __syncthreads();
    int Bsel = selbin;

#pragma unroll
    for (int q = 0; q < 8; q++) {
        if ((int)(fb[q] >> 19) <= Bsel) {
            unsigned pos = atomicAdd(&ccnt, 1u);
            if (pos < CAP)
                cand[pos] = (((unsigned long long)fb[q]) << 32) | (unsigned)(t + q*1024);
        }
    }
    __syncthreads();
    unsigned cnt = min(ccnt, (unsigned)CAP);
    if (t >= cnt && t < CAP) cand[t] = 0x3F800000FFFFFFFFull;
    __syncthreads();

    for (int k = 2; k <= CAP; k <<= 1) {
        for (int j = k >> 1; j > 0; j >>= 1) {
            if (t < CAP) {
                int p = t ^ j;
                if (p > t) {
                    unsigned long long x = cand[t], y = cand[p];
                    bool asc = ((t & k) == 0);
                    if ((x > y) == asc) { cand[t] = y; cand[p] = x; }
                }
            }
            __syncthreads();
        }
    }

    float v = 1.0f;
    if (t < CAP) v = __uint_as_float((unsigned)(cand[t] >> 32));
    float *f0 = (float*)uscan0, *f1 = (float*)uscan1;
    if (t < CAP) f0[t] = v;
    __syncthreads();
    for (int off = 1; off < CAP; off <<= 1) {
        float x = 0.0f;
        if (t < CAP) { x = f0[t]; if (t >= off) x *= f0[t - off]; }
        __syncthreads();
        if (t < CAP) f1[t] = x;
        __syncthreads();
        float* tmp = f0; f0 = f1; f1 = tmp;
    }
    if (t < CAP) {
        float pre = (t == 0) ? 1.0f : f0[t - 1];
        unsigned idx = (unsigned)(cand[t] & 0xFFFFFFFFull);
        if (idx < NN)
            ws[O_ALLOC + (size_t)b * NN + idx] = (1.0f - v) * pre;
    }
}

// ---------- kernel 2: persistent single-pass dots + update, LDS retention ----------
__global__ __launch_bounds__(NTHR2, 4)
void fused_kernel(const float* __restrict__ mem,
                  const float* __restrict__ controls,
                  float* __restrict__ ws,
                  float* __restrict__ out) {
    __shared__ floatx4 sdata[ROWS_PB][WW/4];   // 32 KB: 32 rows held across the wait
    __shared__ float psred[256];               // 1 KB: partial-sum reduce
    __shared__ float wred[NTHR2/64];           // per-wave partials

    const int g   = blockIdx.x;
    const int t   = threadIdx.x;
    const int l   = t & 63;
    const int li  = l & 15;                    // 16 lanes per row
    const int rl  = t >> 4;                    // local row 0..31
    const int blk = g & (BLKS_PB - 1);
    const int half = g >> 8;                   // 0 or 1: which batch of the round

    float* psum = ws + O_PSUM;
    int*   cnt  = (int*)(ws + O_CNT);

    for (int r = 0; r < NROUND; ++r) {
        const int b = r * 2 + half;
        const int myrow = blk * ROWS_PB + rl;
        const float* c = controls + (size_t)b * CDIM;

        // ---------- phase A: stream 32 rows into LDS, dots on the fly ----------
        float4 k4[4];
        float ksq = 0.0f;
#pragma unroll
        for (int k = 0; k < 4; k++) {
            int col = (li + k*16) * 4;
            k4[k].x = c[col + 0];
            k4[k].y = c[col + 1];
            k4[k].z = c[col + 2];
            k4[k].w = c[col + 3];
            ksq += k4[k].x*k4[k].x + k4[k].y*k4[k].y + k4[k].z*k4[k].z + k4[k].w*k4[k].w;
        }
#pragma unroll
        for (int off = 8; off > 0; off >>= 1) ksq += __shfl_xor(ksq, off, 64);
        float kn = sqrtf(ksq);
        float bx = c[3*WW + RR];
        float beta = 1.0f + fmaxf(bx, 0.0f) + log1pf(expf(-fabsf(bx)));

        const floatx4* mrow = (const floatx4*)(mem + ((size_t)b * NN + myrow) * WW);
        float dot = 0.0f, nn2 = 0.0f;
#pragma unroll
        for (int k = 0; k < 4; k++) {
            floatx4 m4 = mrow[li + k*16];
            sdata[rl][li + k*16] = m4;
            dot += m4.x*k4[k].x + m4.y*k4[k].y + m4.z*k4[k].z + m4.w*k4[k].w;
            nn2 += m4.x*m4.x + m4.y*m4.y + m4.z*m4.z + m4.w*m4.w;
        }
#pragma unroll
        for (int off = 8; off > 0; off >>= 1) {
            dot += __shfl_xor(dot, off, 64);
            nn2 += __shfl_xor(nn2, off, 64);
        }
        float pv = expf(dot / (kn * sqrtf(nn2) + EPSF) * beta);  // all 16 lanes same

        // block partial sum (fixed order -> deterministic)
        float val = (li == 0) ? pv : 0.0f;
        val += __shfl_xor(val, 16, 64);
        val += __shfl_xor(val, 32, 64);
        if (l == 0) wred[t >> 6] = val;
        __syncthreads();
        if (t == 0) {
            float s = 0.0f;
#pragma unroll
            for (int j = 0; j < NTHR2/64; j++) s += wred[j];
            __hip_atomic_store(&psum[b*256 + blk], s, __ATOMIC_RELAXED, __HIP_MEMORY_SCOPE_AGENT);
            __hip_atomic_fetch_add(&cnt[b], 1, __ATOMIC_RELEASE, __HIP_MEMORY_SCOPE_AGENT);
        }

        // ---------- wait for all 256 producers of batch b ----------
        if (t == 0) {
            while (__hip_atomic_load(&cnt[b], __ATOMIC_ACQUIRE, __HIP_MEMORY_SCOPE_AGENT) < BLKS_PB)
                __builtin_amdgcn_s_sleep(2);
        }
        __syncthreads();

        // deterministic fixed-order sum of the 256 partials
        if (t < 256)
            psred[t] = __hip_atomic_load(&psum[b*256 + t], __ATOMIC_RELAXED, __HIP_MEMORY_SCOPE_AGENT);
        __syncthreads();
        for (int s = 128; s > 0; s >>= 1) {
            if (t < s) psred[t] += psred[t + s];
            __syncthreads();
        }
        float iden = 1.0f / psred[0];

        // ---------- phase B: update from LDS, NT store ----------
        float ag = sigmoidf_(c[3*WW + RR + 1]);
        float wg = sigmoidf_(c[3*WW + RR + 2]);
        float4 e4[4], a4[4];
#pragma unroll
        for (int k = 0; k < 4; k++) {
            int col = (li + k*16) * 4;
            e4[k].x = sigmoidf_(c[WW + col + 0]);
            e4[k].y = sigmoidf_(c[WW + col + 1]);
            e4[k].z = sigmoidf_(c[WW + col + 2]);
            e4[k].w = sigmoidf_(c[WW + col + 3]);
            a4[k].x = c[2*WW + col + 0];
            a4[k].y = c[2*WW + col + 1];
            a4[k].z = c[2*WW + col + 2];
            a4[k].w = c[2*WW + col + 3];
        }
        float phi = ws[O_PHI   + (size_t)b * NN + myrow];
        float al  = ws[O_ALLOC + (size_t)b * NN + myrow];
        float wwt = wg * (ag * al + (1.0f - ag) * pv * iden);

        floatx4* orow = (floatx4*)(out + ((size_t)b * NN + myrow) * WW);
#pragma unroll
        for (int k = 0; k < 4; k++) {
            floatx4 m4 = sdata[rl][li + k*16];
            floatx4 o;
            o.x = m4.x * (1.0f - wwt * e4[k].x) * phi + wwt * a4[k].x;
            o.y = m4.y * (1.0f - wwt * e4[k].y) * phi + wwt * a4[k].y;
            o.z = m4.z * (1.0f - wwt * e4[k].z) * phi + wwt * a4[k].z;
            o.w = m4.w * (1.0f - wwt * e4[k].w) * phi + wwt * a4[k].w;
            __builtin_nontemporal_store(o, &orow[li + k*16]);
        }
        __syncthreads();   // protect sdata before next round overwrites
    }
}

extern "C" void kernel_launch(void* const* d_in, const int* in_sizes, int n_in,
                              void* d_out, int out_size, void* d_ws, size_t ws_size,
                              hipStream_t stream) {
    const float* mem      = (const float*)d_in[0];
    const float* controls = (const float*)d_in[1];
    const float* rw       = (const float*)d_in[2];
    const float* us       = (const float*)d_in[3];
    const float* pw       = (const float*)d_in[4];
    float* out = (float*)d_out;
    float* ws  = (float*)d_ws;

    topk_kernel<<<BB, 1024, 0, stream>>>(controls, rw, us, pw, ws);
    fused_kernel<<<NBLK2, NTHR2, 0, stream>>>(mem, controls, ws, out);
}

// Round 11
// 143.094 us; speedup vs baseline: 6.7896x; 5.7229x over previous
//
#include <hip/hip_runtime.h>
#include <math.h>

#define BB 32
#define NN 8192
#define WW 256
#define RR 4
#define CDIM (3*WW + RR + 3)   // 775
#define EPSF 1e-8f

#define K_SEL 128
#define CAP   256

typedef float floatx4 __attribute__((ext_vector_type(4)));

// ---- workspace layout (float offsets) ----
#define O_S      0                      // B*N : p = exp(beta*cossim)
#define O_PHI    (O_S     + BB*NN)      // B*N
#define O_ALLOC  (O_PHI   + BB*NN)      // B*N
#define O_PSUM   (O_ALLOC + BB*NN)      // B*32 partial softmax sums

__device__ __forceinline__ float sigmoidf_(float x) { return 1.0f / (1.0f + expf(-x)); }

// ------- kernel 1: role-split. blocks 0..31: phi/usc/topk/alloc.
//                   blocks 32..1055: dots -> p, per-chunk partial sums. -------
__global__ __launch_bounds__(1024) void mid_kernel(const float* __restrict__ mem,
                                                   const float* __restrict__ controls,
                                                   const float* __restrict__ rw,
                                                   const float* __restrict__ us,
                                                   const float* __restrict__ pw,
                                                   float* __restrict__ ws) {
    __shared__ unsigned hist[4096];            // 16 KB (topk role)
    __shared__ unsigned long long cand[CAP];   //  2 KB
    __shared__ unsigned uscan0[1024];          //  4 KB
    __shared__ unsigned uscan1[1024];          //  4 KB
    __shared__ float    dred[64];              // dots role
    __shared__ int selbin;
    __shared__ unsigned ccnt;

    int t = threadIdx.x;

    if (blockIdx.x < BB) {
        // ================= TOP-K role (one block per batch) =================
        int b = blockIdx.x;
        const float* c = controls + (size_t)b * CDIM;
        float fg[RR];
#pragma unroll
        for (int r = 0; r < RR; r++) fg[r] = sigmoidf_(c[3*WW + r]);

        for (int i = t; i < 4096; i += 1024) hist[i] = 0;
        if (t == 0) { selbin = 0x7FFFFFFF; ccnt = 0; }
        __syncthreads();

        unsigned fb[8];
#pragma unroll
        for (int q = 0; q < 8; q++) {
            int n = t + q * 1024;
            size_t gid = (size_t)b * NN + n;
            float phi = 1.0f;
#pragma unroll
            for (int r = 0; r < RR; r++)
                phi *= (1.0f - fg[r] * rw[((size_t)(b*RR + r)) * NN + n]);
            float u0 = us[gid];
            float u = (u0 + pw[gid] * (1.0f - u0)) * phi;
            float usc = u * (1.0f - EPSF) + EPSF;   // strictly positive, <= 1
            ws[O_PHI   + gid] = phi;
            ws[O_ALLOC + gid] = 0.0f;               // scatter fills top-K below
            fb[q] = __float_as_uint(usc);           // bits monotone for +floats
            atomicAdd(&hist[fb[q] >> 19], 1u);
        }
        __syncthreads();

        // cumulative over 4096 bins (4 bins/thread + 1024-scan)
        unsigned h0 = hist[4*t], h1 = hist[4*t+1], h2 = hist[4*t+2], h3 = hist[4*t+3];
        unsigned tot = h0 + h1 + h2 + h3;
        unsigned *a0 = uscan0, *a1 = uscan1;
        a0[t] = tot;
        __syncthreads();
        for (int off = 1; off < 1024; off <<= 1) {
            unsigned v = a0[t];
            if (t >= off) v += a0[t - off];
            a1[t] = v;
            __syncthreads();
            unsigned* tmp = a0; a0 = a1; a1 = tmp;
        }
        unsigned excl = (t == 0) ? 0u : a0[t - 1];
        {
            unsigned cc = excl;
            unsigned hh[4] = {h0, h1, h2, h3};
#pragma unroll
            for (int j = 0; j < 4; j++) {
                cc += hh[j];
                if (cc >= K_SEL) { atomicMin(&selbin, 4*t + j); break; }
            }
        }
        __syncthreads();
        int Bsel = selbin;

#pragma unroll
        for (int q = 0; q < 8; q++) {
            if ((int)(fb[q] >> 19) <= Bsel) {
                unsigned pos = atomicAdd(&ccnt, 1u);
                if (pos < CAP)
                    cand[pos] = (((unsigned long long)fb[q]) << 32) | (unsigned)(t + q*1024);
            }
        }
        __syncthreads();
        unsigned cnt = min(ccnt, (unsigned)CAP);
        if (t >= cnt && t < CAP) cand[t] = 0x3F800000FFFFFFFFull;  // (1.0f, ~0)
        __syncthreads();

        // bitonic sort CAP keys ascending on (value_bits, idx) -> stable
        for (int k = 2; k <= CAP; k <<= 1) {
            for (int j = k >> 1; j > 0; j >>= 1) {
                if (t < CAP) {
                    int l = t ^ j;
                    if (l > t) {
                        unsigned long long x = cand[t], y = cand[l];
                        bool asc = ((t & k) == 0);
                        if ((x > y) == asc) { cand[t] = y; cand[l] = x; }
                    }
                }
                __syncthreads();
            }
        }

        // exclusive cumprod of sorted values (first CAP threads)
        float v = 1.0f;
        if (t < CAP) v = __uint_as_float((unsigned)(cand[t] >> 32));
        float *f0 = (float*)uscan0, *f1 = (float*)uscan1;
        if (t < CAP) f0[t] = v;
        __syncthreads();
        for (int off = 1; off < CAP; off <<= 1) {
            float x = 0.0f;
            if (t < CAP) { x = f0[t]; if (t >= off) x *= f0[t - off]; }
            __syncthreads();
            if (t < CAP) f1[t] = x;
            __syncthreads();
            float* tmp = f0; f0 = f1; f1 = tmp;
        }
        if (t < CAP) {
            float pre = (t == 0) ? 1.0f : f0[t - 1];
            unsigned idx = (unsigned)(cand[t] & 0xFFFFFFFFull);
            if (idx < NN)
                ws[O_ALLOC + (size_t)b * NN + idx] = (1.0f - v) * pre;
        }
    } else {
        // ================= DOTS role (256 rows per block) =================
        int d = blockIdx.x - BB;
        int b = d >> 5;                 // 32 chunks per batch
        int rowbase = (d & 31) << 8;    // *256
        int wave = t >> 6, lane = t & 63;
        int g  = lane >> 4;             // 4 rows per wave per iter
        int li = lane & 15;             // 16 lanes per row

        const float* c = controls + (size_t)b * CDIM;
        // key fragment: lane li holds floats [li*4 + k*64 .. +3], k=0..3
        float4 k4[4];
        float ksq = 0.0f;
#pragma unroll
        for (int k = 0; k < 4; k++) {
            k4[k].x = c[li*4 + k*64 + 0];
            k4[k].y = c[li*4 + k*64 + 1];
            k4[k].z = c[li*4 + k*64 + 2];
            k4[k].w = c[li*4 + k*64 + 3];
            ksq += k4[k].x*k4[k].x + k4[k].y*k4[k].y + k4[k].z*k4[k].z + k4[k].w*k4[k].w;
        }
#pragma unroll
        for (int off = 8; off > 0; off >>= 1) ksq += __shfl_xor(ksq, off, 64);
        float kn = sqrtf(ksq);
        float bx = c[3*WW + RR];
        float beta = 1.0f + fmaxf(bx, 0.0f) + log1pf(expf(-fabsf(bx)));

        float psum = 0.0f;
#pragma unroll
        for (int p = 0; p < 4; p++) {
            int n = rowbase + wave*16 + p*4 + g;
            const float4* mrow = (const float4*)(mem + ((size_t)b * NN + n) * WW);
            float dot = 0.0f, nn2 = 0.0f;
#pragma unroll
            for (int k = 0; k < 4; k++) {
                float4 m = mrow[li + k*16];
                dot += m.x*k4[k].x + m.y*k4[k].y + m.z*k4[k].z + m.w*k4[k].w;
                nn2 += m.x*m.x + m.y*m.y + m.z*m.z + m.w*m.w;
            }
#pragma unroll
            for (int off = 8; off > 0; off >>= 1) {
                dot += __shfl_xor(dot, off, 64);
                nn2 += __shfl_xor(nn2, off, 64);
            }
            if (li == 0) {
                float pv = expf(dot / (kn * sqrtf(nn2) + EPSF) * beta);
                ws[O_S + (size_t)b * NN + n] = pv;
                psum += pv;
            }
        }
        if (li == 0) dred[wave*4 + g] = psum;
        __syncthreads();
        if (t == 0) {
            float s = 0.0f;
#pragma unroll
            for (int i = 0; i < 64; i++) s += dred[i];
            ws[O_PSUM + b*32 + (d & 31)] = s;
        }
    }
}

// ---------------- kernel 2: fused erase/add update (reverse order) ----------------
__global__ __launch_bounds__(256) void update_kernel(const float* __restrict__ mem,
                                                     const float* __restrict__ controls,
                                                     const float* __restrict__ ws,
                                                     float* __restrict__ out) {
    int bid = gridDim.x - 1 - blockIdx.x;     // reverse: reuse L3-resident tail of mem
    int b  = bid >> 7;
    int rb = (bid & 127) << 6;
    int wave = threadIdx.x >> 6, lane = threadIdx.x & 63;

    const float* c = controls + (size_t)b * CDIM;
    float4 e4, a4;
    e4.x = sigmoidf_(c[WW + lane*4 + 0]);
    e4.y = sigmoidf_(c[WW + lane*4 + 1]);
    e4.z = sigmoidf_(c[WW + lane*4 + 2]);
    e4.w = sigmoidf_(c[WW + lane*4 + 3]);
    a4.x = c[2*WW + lane*4 + 0];
    a4.y = c[2*WW + lane*4 + 1];
    a4.z = c[2*WW + lane*4 + 2];
    a4.w = c[2*WW + lane*4 + 3];
    float ag = sigmoidf_(c[3*WW + RR + 1]);
    float wg = sigmoidf_(c[3*WW + RR + 2]);

    float sum = 0.0f;
#pragma unroll
    for (int i = 0; i < 32; i++) sum += ws[O_PSUM + b*32 + i];
    float iden = 1.0f / sum;

#pragma unroll 4
    for (int it = 0; it < 16; ++it) {
        int n = rb + it*4 + wave;
        size_t row = (size_t)b * NN + n;
        float pv  = ws[O_S + row];
        float al  = ws[O_ALLOC + row];
        float phi = ws[O_PHI + row];
        float cw  = pv * iden;
        float wwt = wg * (ag * al + (1.0f - ag) * cw);
        float4 m = ((const float4*)(mem + row * WW))[lane];
        floatx4 o;
        o.x = m.x * (1.0f - wwt * e4.x) * phi + wwt * a4.x;
        o.y = m.y * (1.0f - wwt * e4.y) * phi + wwt * a4.y;
        o.z = m.z * (1.0f - wwt * e4.z) * phi + wwt * a4.z;
        o.w = m.w * (1.0f - wwt * e4.w) * phi + wwt * a4.w;
        __builtin_nontemporal_store(o, &((floatx4*)(out + row * WW))[lane]);
    }
}

extern "C" void kernel_launch(void* const* d_in, const int* in_sizes, int n_in,
                              void* d_out, int out_size, void* d_ws, size_t ws_size,
                              hipStream_t stream) {
    const float* mem      = (const float*)d_in[0];
    const float* controls = (const float*)d_in[1];
    const float* rw       = (const float*)d_in[2];
    const float* us       = (const float*)d_in[3];
    const float* pw       = (const float*)d_in[4];
    float* out = (float*)d_out;
    float* ws  = (float*)d_ws;

    mid_kernel<<<BB + BB * (NN / 256), 1024, 0, stream>>>(mem, controls, rw, us, pw, ws);
    update_kernel<<<BB * (NN / 64), 256, 0, stream>>>(mem, controls, ws, out);
}